// Round 1
// baseline (1279.900 us; speedup 1.0000x reference)
//
#include <hip/hip_runtime.h>
#include <cstdint>

#define SDIM 512
#define BDIM 64
#define HDIM 1024
#define VDIM 50257

typedef unsigned short ushort_t;
typedef __attribute__((ext_vector_type(8))) short short8;
typedef __attribute__((ext_vector_type(4))) float f32x4;

static __device__ __forceinline__ ushort_t f2b(float f) {
    unsigned int u = __float_as_uint(f);
    unsigned int r = (u + 0x7FFFu + ((u >> 16) & 1u)) >> 16;   // RNE fp32->bf16
    return (ushort_t)r;
}

// ---- GRU: gxT[j, b] = sum_k W_ih[j,k] * x[b,k] ----
__global__ __launch_bounds__(512) void k_gru_gemm(const float* __restrict__ x,
        const float* __restrict__ Wih, float* __restrict__ gxT) {
    __shared__ float xs[64 * 129];
    const int tid = threadIdx.x;
    const int lane = tid & 63;                 // = b
    const int wv = tid >> 6;                   // 0..7
    const int j = blockIdx.x * 8 + wv;         // 0..3071
    const int row = tid >> 3;                  // staging row 0..63
    const int cq = (tid & 7) * 4;              // staging float4 base
    float acc = 0.f;
    for (int k0 = 0; k0 < 1024; k0 += 128) {
        __syncthreads();
        const float4* xsrc = (const float4*)(x + row * 1024 + k0);
        #pragma unroll
        for (int i = 0; i < 4; ++i) {
            float4 v = xsrc[cq + i];
            float* dst = &xs[row * 129 + (cq + i) * 4];
            dst[0] = v.x; dst[1] = v.y; dst[2] = v.z; dst[3] = v.w;
        }
        __syncthreads();
        const float4* wsrc = (const float4*)(Wih + j * 1024 + k0);
        #pragma unroll 8
        for (int k4 = 0; k4 < 32; ++k4) {
            float4 w4 = wsrc[k4];
            const float* xr = &xs[lane * 129 + k4 * 4];
            acc += w4.x * xr[0] + w4.y * xr[1] + w4.z * xr[2] + w4.w * xr[3];
        }
    }
    gxT[j * 64 + lane] = acc;
}

// ---- gates: h = (1-z)*n  (h0 == 0 so gh == b_hh) ----
__global__ __launch_bounds__(256) void k_gru_gates(const float* __restrict__ gxT,
        const float* __restrict__ b_ih, const float* __restrict__ b_hh,
        float* __restrict__ h, float* __restrict__ h_out, ushort_t* __restrict__ catb) {
    int idx = blockIdx.x * 256 + threadIdx.x;  // 0..65535
    int b = idx & 63;
    int j = idx >> 6;
    float gr = gxT[j * 64 + b] + b_ih[j] + b_hh[j];
    float gz = gxT[(j + 1024) * 64 + b] + b_ih[j + 1024] + b_hh[j + 1024];
    float xn = gxT[(j + 2048) * 64 + b] + b_ih[j + 2048];
    float hn = b_hh[j + 2048];
    float r = 1.f / (1.f + expf(-gr));
    float z = 1.f / (1.f + expf(-gz));
    float n = tanhf(xn + r * hn);
    float hv = (1.f - z) * n;
    h[b * 1024 + j] = hv;
    h_out[b * 1024 + j] = hv;
    catb[b * 2048 + j] = f2b(hv);
}

// ---- P[b, col] = sum_i h[b,i] * attn_W[i, col]   (col 0..2047) ----
__global__ __launch_bounds__(256) void k_attn_proj(const float* __restrict__ h,
        const float* __restrict__ attn_W, float* __restrict__ P) {
    __shared__ float hl[8][64];
    const int col = blockIdx.x * 256 + threadIdx.x;
    const int b0 = blockIdx.y * 8;
    float acc[8] = {0,0,0,0,0,0,0,0};
    for (int i0 = 0; i0 < 1024; i0 += 64) {
        __syncthreads();
        for (int t = threadIdx.x; t < 512; t += 256)
            hl[t >> 6][t & 63] = h[(b0 + (t >> 6)) * 1024 + i0 + (t & 63)];
        __syncthreads();
        #pragma unroll 8
        for (int ii = 0; ii < 64; ++ii) {
            float w = attn_W[(i0 + ii) * 2048 + col];
            #pragma unroll
            for (int bb = 0; bb < 8; ++bb) acc[bb] += hl[bb][ii] * w;
        }
    }
    #pragma unroll
    for (int bb = 0; bb < 8; ++bb) P[(b0 + bb) * 2048 + col] = acc[bb];
}

// ---- c[b] = sum_j (P[b,j] + attn_b[j]) * h[b,j] ----
__global__ __launch_bounds__(64) void k_attn_c(const float* __restrict__ P,
        const float* __restrict__ h, const float* __restrict__ attn_b,
        float* __restrict__ cvec) {
    int b = blockIdx.x;
    int lane = threadIdx.x;
    float acc = 0.f;
    #pragma unroll
    for (int k = 0; k < 16; ++k) {
        int j = lane + 64 * k;
        acc += (P[b * 2048 + j] + attn_b[j]) * h[b * 1024 + j];
    }
    #pragma unroll
    for (int off = 32; off > 0; off >>= 1) acc += __shfl_xor(acc, off);
    if (lane == 0) cvec[b] = acc;
}

// ---- scores[b,s] = c[b] + enc[s,b,:] . u[b,:]   (u = P[:,1024:]) ----
__global__ __launch_bounds__(256) void k_scores(const float* __restrict__ enc,
        const float* __restrict__ P, const float* __restrict__ cvec,
        float* __restrict__ scores) {
    int id = blockIdx.x * 4 + (threadIdx.x >> 6);   // 0..32767
    int lane = threadIdx.x & 63;
    int s = id >> 6;
    int b = id & 63;
    const float4* e4 = (const float4*)(enc + (size_t)(s * 64 + b) * 1024);
    const float4* u4 = (const float4*)(P + b * 2048 + 1024);
    float acc = 0.f;
    #pragma unroll
    for (int k = 0; k < 4; ++k) {
        float4 a = e4[lane + 64 * k];
        float4 u = u4[lane + 64 * k];
        acc += a.x * u.x + a.y * u.y + a.z * u.z + a.w * u.w;
    }
    #pragma unroll
    for (int off = 32; off > 0; off >>= 1) acc += __shfl_xor(acc, off);
    if (lane == 0) scores[b * 512 + s] = acc + cvec[b];
}

// ---- softmax over s (512) per b ----
__global__ __launch_bounds__(256) void k_softmax(const float* __restrict__ scores,
        float* __restrict__ wout) {
    __shared__ float red[256];
    int b = blockIdx.x;
    int t = threadIdx.x;
    float s1 = scores[b * 512 + t];
    float s2 = scores[b * 512 + t + 256];
    red[t] = fmaxf(s1, s2);
    __syncthreads();
    for (int o = 128; o > 0; o >>= 1) { if (t < o) red[t] = fmaxf(red[t], red[t + o]); __syncthreads(); }
    float bm = red[0];
    __syncthreads();
    float e1 = expf(s1 - bm), e2 = expf(s2 - bm);
    red[t] = e1 + e2;
    __syncthreads();
    for (int o = 128; o > 0; o >>= 1) { if (t < o) red[t] += red[t + o]; __syncthreads(); }
    float inv = 1.f / red[0];
    wout[b * 512 + t] = e1 * inv;
    wout[b * 512 + t + 256] = e2 * inv;
}

// ---- context[b,e] = sum_s w[b,s] * enc[s,b,e] -> cat_bf16[b][1024+e] ----
__global__ __launch_bounds__(256) void k_context(const float* __restrict__ enc,
        const float* __restrict__ w, ushort_t* __restrict__ catb) {
    __shared__ float wl[512];
    int b = blockIdx.y;
    int e = blockIdx.x * 256 + threadIdx.x;
    wl[threadIdx.x] = w[b * 512 + threadIdx.x];
    wl[threadIdx.x + 256] = w[b * 512 + threadIdx.x + 256];
    __syncthreads();
    float acc = 0.f;
    #pragma unroll 4
    for (int s = 0; s < 512; ++s)
        acc += wl[s] * enc[(size_t)(s * 64 + b) * 1024 + e];
    catb[b * 2048 + 1024 + e] = f2b(acc);
}

// ---- dec[b,v] = cat[b,:] . out_W[v,:] + out_b[v]  via bf16 MFMA ----
__global__ __launch_bounds__(256) void k_dec_gemm(const ushort_t* __restrict__ catb,
        const float* __restrict__ outW, const float* __restrict__ outb,
        float* __restrict__ out0) {
    __shared__ __align__(16) ushort_t bT[64 * 72];   // [v_row][k] padded +8
    const int tid = threadIdx.x;
    const int v0 = blockIdx.x * 64;
    const int lane = tid & 63;
    const int wv = tid >> 6;        // wave 0..3 -> b-strip
    const int quad = lane >> 4;
    const int l15 = lane & 15;
    const int srow = tid >> 2;      // staging: 0..63
    const int sq = tid & 3;
    f32x4 acc0 = {0,0,0,0}, acc1 = {0,0,0,0}, acc2 = {0,0,0,0}, acc3 = {0,0,0,0};
    const bool rowok = (v0 + srow) < VDIM;
    const float4* wrow = (const float4*)(outW + (size_t)(v0 + srow) * 2048);
    const ushort_t* arow = catb + (16 * wv + l15) * 2048 + quad * 8;

    for (int c = 0; c < 32; ++c) {          // K chunks of 64
        __syncthreads();
        #pragma unroll
        for (int i = 0; i < 4; ++i) {
            int f4 = sq * 4 + i;            // float4 index within 64-float chunk
            float4 v = rowok ? wrow[c * 16 + f4] : make_float4(0.f, 0.f, 0.f, 0.f);
            ushort_t* d = &bT[srow * 72 + f4 * 4];
            d[0] = f2b(v.x); d[1] = f2b(v.y); d[2] = f2b(v.z); d[3] = f2b(v.w);
        }
        __syncthreads();
        #pragma unroll
        for (int ks = 0; ks < 2; ++ks) {
            short8 a = *(const short8*)(arow + c * 64 + ks * 32);
            const ushort_t* bbase = &bT[l15 * 72 + ks * 32 + quad * 8];
            short8 b0 = *(const short8*)(bbase);
            short8 b1 = *(const short8*)(bbase + 16 * 72);
            short8 b2 = *(const short8*)(bbase + 32 * 72);
            short8 b3 = *(const short8*)(bbase + 48 * 72);
            acc0 = __builtin_amdgcn_mfma_f32_16x16x32_bf16(a, b0, acc0, 0, 0, 0);
            acc1 = __builtin_amdgcn_mfma_f32_16x16x32_bf16(a, b1, acc1, 0, 0, 0);
            acc2 = __builtin_amdgcn_mfma_f32_16x16x32_bf16(a, b2, acc2, 0, 0, 0);
            acc3 = __builtin_amdgcn_mfma_f32_16x16x32_bf16(a, b3, acc3, 0, 0, 0);
        }
    }
    int vb = v0 + l15;
    #pragma unroll
    for (int t = 0; t < 4; ++t) {
        f32x4 a = (t == 0) ? acc0 : (t == 1) ? acc1 : (t == 2) ? acc2 : acc3;
        int v = vb + 16 * t;
        if (v < VDIM) {
            float bias = outb[v];
            #pragma unroll
            for (int r = 0; r < 4; ++r) {
                int brow = 16 * wv + quad * 4 + r;   // D: row = quad*4 + reg
                out0[brow * VDIM + v] = a[r] + bias;
            }
        }
    }
}

// ---- per-b logsumexp over V ----
__global__ __launch_bounds__(256) void k_lse(const float* __restrict__ out0,
        float* __restrict__ lse) {
    __shared__ float red[256];
    int b = blockIdx.x;
    int t = threadIdx.x;
    const float* row = out0 + (size_t)b * VDIM;
    float m = -1e30f;
    for (int v = t; v < VDIM; v += 256) m = fmaxf(m, row[v]);
    red[t] = m; __syncthreads();
    for (int o = 128; o > 0; o >>= 1) { if (t < o) red[t] = fmaxf(red[t], red[t + o]); __syncthreads(); }
    float bm = red[0]; __syncthreads();
    float s = 0.f;
    for (int v = t; v < VDIM; v += 256) s += expf(row[v] - bm);
    red[t] = s; __syncthreads();
    for (int o = 128; o > 0; o >>= 1) { if (t < o) red[t] += red[t + o]; __syncthreads(); }
    if (t == 0) lse[b] = bm + logf(red[0]);
}

__global__ __launch_bounds__(256) void k_lse_apply(float* __restrict__ out0,
        const float* __restrict__ lse) {
    int b = blockIdx.y;
    int v = blockIdx.x * 256 + threadIdx.x;
    if (v < VDIM) out0[(size_t)b * VDIM + v] -= lse[b];
}

extern "C" void kernel_launch(void* const* d_in, const int* in_sizes, int n_in,
                              void* d_out, int out_size, void* d_ws, size_t ws_size,
                              hipStream_t stream) {
    const float* x     = (const float*)d_in[0];
    const float* enc   = (const float*)d_in[1];
    const float* Wih   = (const float*)d_in[3];
    // d_in[4] (W_hh) unused: h0 == 0
    const float* bih   = (const float*)d_in[5];
    const float* bhh   = (const float*)d_in[6];
    const float* attnW = (const float*)d_in[7];
    const float* attnb = (const float*)d_in[8];
    const float* outW  = (const float*)d_in[9];
    const float* outb  = (const float*)d_in[10];

    float* out  = (float*)d_out;
    float* out0 = out;                            // decoder_output 64*50257
    float* outh = out + (size_t)VDIM * 64;        // h (1,64,1024)
    float* outw = outh + 64 * 1024;               // attn_weights (64,512)

    float* ws     = (float*)d_ws;
    float* gxT    = ws;                // 3072*64
    float* h      = ws + 196608;       // 64*1024
    float* P      = ws + 262144;       // 64*2048
    float* cvec   = ws + 393216;       // 64
    float* scores = ws + 393280;       // 64*512
    float* lse    = ws + 426048;       // 64
    ushort_t* catb = (ushort_t*)(ws + 426112);    // 64*2048 bf16

    k_gru_gemm<<<384, 512, 0, stream>>>(x, Wih, gxT);
    k_gru_gates<<<256, 256, 0, stream>>>(gxT, bih, bhh, h, outh, catb);
    k_attn_proj<<<dim3(8, 8), 256, 0, stream>>>(h, attnW, P);
    k_attn_c<<<64, 64, 0, stream>>>(P, h, attnb, cvec);
    k_scores<<<8192, 256, 0, stream>>>(enc, P, cvec, scores);
    k_softmax<<<64, 256, 0, stream>>>(scores, outw);
    k_context<<<dim3(4, 64), 256, 0, stream>>>(enc, outw, catb);
    k_dec_gemm<<<786, 256, 0, stream>>>(catb, outW, outb, out0);
    k_lse<<<64, 256, 0, stream>>>(out0, lse);
    k_lse_apply<<<dim3(197, 64), 256, 0, stream>>>(out0, lse);
}

// Round 2
// 790.506 us; speedup vs baseline: 1.6191x; 1.6191x over previous
//
#include <hip/hip_runtime.h>
#include <cstdint>

#define SDIM 512
#define BDIM 64
#define HDIM 1024
#define VDIM 50257

typedef unsigned short ushort_t;
typedef __attribute__((ext_vector_type(8))) short short8;
typedef __attribute__((ext_vector_type(4))) float f32x4;

static __device__ __forceinline__ ushort_t f2b(float f) {
    unsigned int u = __float_as_uint(f);
    unsigned int r = (u + 0x7FFFu + ((u >> 16) & 1u)) >> 16;   // RNE fp32->bf16
    return (ushort_t)r;
}

// ---- GRU: gxT[j, b] = sum_k W_ih[j,k] * x[b,k] ----
__global__ __launch_bounds__(512) void k_gru_gemm(const float* __restrict__ x,
        const float* __restrict__ Wih, float* __restrict__ gxT) {
    __shared__ float xs[64 * 129];
    const int tid = threadIdx.x;
    const int lane = tid & 63;                 // = b
    const int wv = tid >> 6;                   // 0..7
    const int j = blockIdx.x * 8 + wv;         // 0..3071
    const int row = tid >> 3;                  // staging row 0..63
    const int cq = (tid & 7) * 4;              // staging float4 base
    float acc = 0.f;
    for (int k0 = 0; k0 < 1024; k0 += 128) {
        __syncthreads();
        const float4* xsrc = (const float4*)(x + row * 1024 + k0);
        #pragma unroll
        for (int i = 0; i < 4; ++i) {
            float4 v = xsrc[cq + i];
            float* dst = &xs[row * 129 + (cq + i) * 4];
            dst[0] = v.x; dst[1] = v.y; dst[2] = v.z; dst[3] = v.w;
        }
        __syncthreads();
        const float4* wsrc = (const float4*)(Wih + j * 1024 + k0);
        #pragma unroll 8
        for (int k4 = 0; k4 < 32; ++k4) {
            float4 w4 = wsrc[k4];
            const float* xr = &xs[lane * 129 + k4 * 4];
            acc += w4.x * xr[0] + w4.y * xr[1] + w4.z * xr[2] + w4.w * xr[3];
        }
    }
    gxT[j * 64 + lane] = acc;
}

// ---- gates: h = (1-z)*n  (h0 == 0 so gh == b_hh) ----
__global__ __launch_bounds__(256) void k_gru_gates(const float* __restrict__ gxT,
        const float* __restrict__ b_ih, const float* __restrict__ b_hh,
        float* __restrict__ h, float* __restrict__ h_out, ushort_t* __restrict__ catb) {
    int idx = blockIdx.x * 256 + threadIdx.x;  // 0..65535
    int b = idx & 63;
    int j = idx >> 6;
    float gr = gxT[j * 64 + b] + b_ih[j] + b_hh[j];
    float gz = gxT[(j + 1024) * 64 + b] + b_ih[j + 1024] + b_hh[j + 1024];
    float xn = gxT[(j + 2048) * 64 + b] + b_ih[j + 2048];
    float hn = b_hh[j + 2048];
    float r = 1.f / (1.f + expf(-gr));
    float z = 1.f / (1.f + expf(-gz));
    float n = tanhf(xn + r * hn);
    float hv = (1.f - z) * n;
    h[b * 1024 + j] = hv;
    h_out[b * 1024 + j] = hv;
    catb[b * 2048 + j] = f2b(hv);
}

// ---- split-K attn proj: Ppart[kc][b][col] = sum_{k in chunk kc} h[b,k]*attn_W[k,col] ----
__global__ __launch_bounds__(256) void k_attn_proj(const float* __restrict__ h,
        const float* __restrict__ attn_W, float* __restrict__ Ppart) {
    __shared__ float hl[64][68];
    const int tid = threadIdx.x;
    const int col = blockIdx.x * 64 + (tid & 63);
    const int g = tid >> 6;            // 0..3 -> 16 b's each
    const int k0 = blockIdx.y * 64;
    {
        int b = tid >> 2;
        int q = tid & 3;
        const float4* src = (const float4*)(h + b * 1024 + k0);
        #pragma unroll
        for (int i = 0; i < 4; ++i) {
            float4 v = src[q * 4 + i];
            float* dst = &hl[b][(q * 4 + i) * 4];
            dst[0] = v.x; dst[1] = v.y; dst[2] = v.z; dst[3] = v.w;
        }
    }
    __syncthreads();
    float acc[16];
    #pragma unroll
    for (int i = 0; i < 16; ++i) acc[i] = 0.f;
    #pragma unroll 4
    for (int kk = 0; kk < 64; ++kk) {
        float w = attn_W[(size_t)(k0 + kk) * 2048 + col];
        #pragma unroll
        for (int bb = 0; bb < 16; ++bb)
            acc[bb] += hl[g * 16 + bb][kk] * w;
    }
    float* dst = Ppart + (size_t)blockIdx.y * 64 * 2048;
    #pragma unroll
    for (int bb = 0; bb < 16; ++bb)
        dst[(g * 16 + bb) * 2048 + col] = acc[bb];
}

// ---- P[idx] = sum_kc Ppart[kc][idx] ----
__global__ __launch_bounds__(256) void k_attn_reduce(const float* __restrict__ Ppart,
        float* __restrict__ P) {
    int idx = blockIdx.x * 256 + threadIdx.x;   // < 131072
    float s = 0.f;
    #pragma unroll
    for (int kc = 0; kc < 16; ++kc) s += Ppart[kc * 131072 + idx];
    P[idx] = s;
}

// ---- c[b] = sum_j (P[b,j] + attn_b[j]) * h[b,j] ----
__global__ __launch_bounds__(64) void k_attn_c(const float* __restrict__ P,
        const float* __restrict__ h, const float* __restrict__ attn_b,
        float* __restrict__ cvec) {
    int b = blockIdx.x;
    int lane = threadIdx.x;
    float acc = 0.f;
    #pragma unroll
    for (int k = 0; k < 16; ++k) {
        int j = lane + 64 * k;
        acc += (P[b * 2048 + j] + attn_b[j]) * h[b * 1024 + j];
    }
    #pragma unroll
    for (int off = 32; off > 0; off >>= 1) acc += __shfl_xor(acc, off);
    if (lane == 0) cvec[b] = acc;
}

// ---- scores[b,s] = c[b] + enc[s,b,:] . u[b,:]   (u = P[:,1024:]) ----
__global__ __launch_bounds__(256) void k_scores(const float* __restrict__ enc,
        const float* __restrict__ P, const float* __restrict__ cvec,
        float* __restrict__ scores) {
    int id = blockIdx.x * 4 + (threadIdx.x >> 6);   // 0..32767
    int lane = threadIdx.x & 63;
    int s = id >> 6;
    int b = id & 63;
    const float4* e4 = (const float4*)(enc + (size_t)(s * 64 + b) * 1024);
    const float4* u4 = (const float4*)(P + b * 2048 + 1024);
    float acc = 0.f;
    #pragma unroll
    for (int k = 0; k < 4; ++k) {
        float4 a = e4[lane + 64 * k];
        float4 u = u4[lane + 64 * k];
        acc += a.x * u.x + a.y * u.y + a.z * u.z + a.w * u.w;
    }
    #pragma unroll
    for (int off = 32; off > 0; off >>= 1) acc += __shfl_xor(acc, off);
    if (lane == 0) scores[b * 512 + s] = acc + cvec[b];
}

// ---- softmax over s (512) per b ----
__global__ __launch_bounds__(256) void k_softmax(const float* __restrict__ scores,
        float* __restrict__ wout) {
    __shared__ float red[256];
    int b = blockIdx.x;
    int t = threadIdx.x;
    float s1 = scores[b * 512 + t];
    float s2 = scores[b * 512 + t + 256];
    red[t] = fmaxf(s1, s2);
    __syncthreads();
    for (int o = 128; o > 0; o >>= 1) { if (t < o) red[t] = fmaxf(red[t], red[t + o]); __syncthreads(); }
    float bm = red[0];
    __syncthreads();
    float e1 = expf(s1 - bm), e2 = expf(s2 - bm);
    red[t] = e1 + e2;
    __syncthreads();
    for (int o = 128; o > 0; o >>= 1) { if (t < o) red[t] += red[t + o]; __syncthreads(); }
    float inv = 1.f / red[0];
    wout[b * 512 + t] = e1 * inv;
    wout[b * 512 + t + 256] = e2 * inv;
}

// ---- split-s context partials: ctxpart[sc][b][e] ----
__global__ __launch_bounds__(256) void k_context(const float* __restrict__ enc,
        const float* __restrict__ w, float* __restrict__ ctxpart) {
    __shared__ float wl[128];
    int b = blockIdx.y;
    int sc = blockIdx.z;
    int e = blockIdx.x * 256 + threadIdx.x;
    if (threadIdx.x < 128) wl[threadIdx.x] = w[b * 512 + sc * 128 + threadIdx.x];
    __syncthreads();
    float acc = 0.f;
    #pragma unroll 4
    for (int s = 0; s < 128; ++s)
        acc += wl[s] * enc[(size_t)((sc * 128 + s) * 64 + b) * 1024 + e];
    ctxpart[((size_t)sc * 64 + b) * 1024 + e] = acc;
}

// ---- catb[b][1024+e] = bf16(sum_sc ctxpart[sc][b][e]) ----
__global__ __launch_bounds__(256) void k_ctx_reduce(const float* __restrict__ ctxpart,
        ushort_t* __restrict__ catb) {
    int idx = blockIdx.x * 256 + threadIdx.x;   // < 65536
    int b = idx >> 10;
    int e = idx & 1023;
    float s = 0.f;
    #pragma unroll
    for (int sc = 0; sc < 4; ++sc) s += ctxpart[sc * 65536 + idx];
    catb[b * 2048 + 1024 + e] = f2b(s);
}

// ---- dec[b,v] = cat[b,:] . out_W[v,:] + out_b[v]  via bf16 MFMA ----
__global__ __launch_bounds__(256) void k_dec_gemm(const ushort_t* __restrict__ catb,
        const float* __restrict__ outW, const float* __restrict__ outb,
        float* __restrict__ out0) {
    __shared__ __align__(16) ushort_t bT[64 * 72];   // [v_row][k] padded +8
    const int tid = threadIdx.x;
    const int v0 = blockIdx.x * 64;
    const int lane = tid & 63;
    const int wv = tid >> 6;        // wave 0..3 -> b-strip
    const int quad = lane >> 4;
    const int l15 = lane & 15;
    const int srow = tid >> 2;      // staging: 0..63
    const int sq = tid & 3;
    f32x4 acc0 = {0,0,0,0}, acc1 = {0,0,0,0}, acc2 = {0,0,0,0}, acc3 = {0,0,0,0};
    const bool rowok = (v0 + srow) < VDIM;
    const float4* wrow = (const float4*)(outW + (size_t)(v0 + srow) * 2048);
    const ushort_t* arow = catb + (16 * wv + l15) * 2048 + quad * 8;

    for (int c = 0; c < 32; ++c) {          // K chunks of 64
        __syncthreads();
        #pragma unroll
        for (int i = 0; i < 4; ++i) {
            int f4 = sq * 4 + i;            // float4 index within 64-float chunk
            float4 v = rowok ? wrow[c * 16 + f4] : make_float4(0.f, 0.f, 0.f, 0.f);
            ushort_t* d = &bT[srow * 72 + f4 * 4];
            d[0] = f2b(v.x); d[1] = f2b(v.y); d[2] = f2b(v.z); d[3] = f2b(v.w);
        }
        __syncthreads();
        #pragma unroll
        for (int ks = 0; ks < 2; ++ks) {
            short8 a = *(const short8*)(arow + c * 64 + ks * 32);
            const ushort_t* bbase = &bT[l15 * 72 + ks * 32 + quad * 8];
            short8 b0 = *(const short8*)(bbase);
            short8 b1 = *(const short8*)(bbase + 16 * 72);
            short8 b2 = *(const short8*)(bbase + 32 * 72);
            short8 b3 = *(const short8*)(bbase + 48 * 72);
            acc0 = __builtin_amdgcn_mfma_f32_16x16x32_bf16(a, b0, acc0, 0, 0, 0);
            acc1 = __builtin_amdgcn_mfma_f32_16x16x32_bf16(a, b1, acc1, 0, 0, 0);
            acc2 = __builtin_amdgcn_mfma_f32_16x16x32_bf16(a, b2, acc2, 0, 0, 0);
            acc3 = __builtin_amdgcn_mfma_f32_16x16x32_bf16(a, b3, acc3, 0, 0, 0);
        }
    }
    int vb = v0 + l15;
    #pragma unroll
    for (int t = 0; t < 4; ++t) {
        f32x4 a = (t == 0) ? acc0 : (t == 1) ? acc1 : (t == 2) ? acc2 : acc3;
        int v = vb + 16 * t;
        if (v < VDIM) {
            float bias = outb[v];
            #pragma unroll
            for (int r = 0; r < 4; ++r) {
                int brow = 16 * wv + quad * 4 + r;   // D: row = quad*4 + reg
                out0[brow * VDIM + v] = a[r] + bias;
            }
        }
    }
}

// ---- split-V logsumexp partials ----
__global__ __launch_bounds__(256) void k_lse_part(const float* __restrict__ out0,
        float* __restrict__ mpart, float* __restrict__ spart) {
    __shared__ float red[256];
    int b = blockIdx.y;
    int c = blockIdx.x;          // 0..7
    int t = threadIdx.x;
    int v0 = c * 6283;
    int v1 = min(v0 + 6283, VDIM);
    const float* row = out0 + (size_t)b * VDIM;
    float m = -1e30f;
    for (int v = v0 + t; v < v1; v += 256) m = fmaxf(m, row[v]);
    red[t] = m; __syncthreads();
    for (int o = 128; o > 0; o >>= 1) { if (t < o) red[t] = fmaxf(red[t], red[t + o]); __syncthreads(); }
    float bm = red[0]; __syncthreads();
    float s = 0.f;
    for (int v = v0 + t; v < v1; v += 256) s += expf(row[v] - bm);
    red[t] = s; __syncthreads();
    for (int o = 128; o > 0; o >>= 1) { if (t < o) red[t] += red[t + o]; __syncthreads(); }
    if (t == 0) { mpart[b * 8 + c] = bm; spart[b * 8 + c] = red[0]; }
}

__global__ __launch_bounds__(64) void k_lse_comb(const float* __restrict__ mpart,
        const float* __restrict__ spart, float* __restrict__ lse) {
    int b = threadIdx.x;
    float M = -1e30f;
    #pragma unroll
    for (int c = 0; c < 8; ++c) M = fmaxf(M, mpart[b * 8 + c]);
    float S = 0.f;
    #pragma unroll
    for (int c = 0; c < 8; ++c) S += spart[b * 8 + c] * expf(mpart[b * 8 + c] - M);
    lse[b] = M + logf(S);
}

__global__ __launch_bounds__(256) void k_lse_apply(float* __restrict__ out0,
        const float* __restrict__ lse) {
    int b = blockIdx.y;
    int v = blockIdx.x * 256 + threadIdx.x;
    if (v < VDIM) out0[(size_t)b * VDIM + v] -= lse[b];
}

extern "C" void kernel_launch(void* const* d_in, const int* in_sizes, int n_in,
                              void* d_out, int out_size, void* d_ws, size_t ws_size,
                              hipStream_t stream) {
    const float* x     = (const float*)d_in[0];
    const float* enc   = (const float*)d_in[1];
    const float* Wih   = (const float*)d_in[3];
    // d_in[4] (W_hh) unused: h0 == 0
    const float* bih   = (const float*)d_in[5];
    const float* bhh   = (const float*)d_in[6];
    const float* attnW = (const float*)d_in[7];
    const float* attnb = (const float*)d_in[8];
    const float* outW  = (const float*)d_in[9];
    const float* outb  = (const float*)d_in[10];

    float* out  = (float*)d_out;
    float* out0 = out;                            // decoder_output 64*50257
    float* outh = out + (size_t)VDIM * 64;        // h (1,64,1024)
    float* outw = outh + 64 * 1024;               // attn_weights (64,512)

    float* ws      = (float*)d_ws;
    float* gxT     = ws;                 // 3072*64 = 196608
    float* h       = ws + 196608;        // 64*1024
    float* P       = ws + 262144;        // 64*2048
    float* cvec    = ws + 393216;        // 64
    float* scores  = ws + 393280;        // 64*512
    float* lse     = ws + 426048;        // 64
    float* mpart   = ws + 426112;        // 64*8
    float* spart   = ws + 426624;        // 64*8
    ushort_t* catb = (ushort_t*)(ws + 427136);    // 64*2048 bf16 (16B-aligned)
    float* Ppart   = ws + 524288;        // 16*64*2048 = 2097152
    float* ctxpart = ws + 2621440;       // 4*64*1024 = 262144  (ends ~11.5 MB)

    k_gru_gemm<<<384, 512, 0, stream>>>(x, Wih, gxT);
    k_gru_gates<<<256, 256, 0, stream>>>(gxT, bih, bhh, h, outh, catb);
    k_attn_proj<<<dim3(32, 16), 256, 0, stream>>>(h, attnW, Ppart);
    k_attn_reduce<<<512, 256, 0, stream>>>(Ppart, P);
    k_attn_c<<<64, 64, 0, stream>>>(P, h, attnb, cvec);
    k_scores<<<8192, 256, 0, stream>>>(enc, P, cvec, scores);
    k_softmax<<<64, 256, 0, stream>>>(scores, outw);
    k_context<<<dim3(4, 64, 4), 256, 0, stream>>>(enc, outw, ctxpart);
    k_ctx_reduce<<<256, 256, 0, stream>>>(ctxpart, catb);
    k_dec_gemm<<<786, 256, 0, stream>>>(catb, outW, outb, out0);
    k_lse_part<<<dim3(8, 64), 256, 0, stream>>>(out0, mpart, spart);
    k_lse_comb<<<1, 64, 0, stream>>>(mpart, spart, lse);
    k_lse_apply<<<dim3(197, 64), 256, 0, stream>>>(out0, lse);
}